// Round 1
// baseline (136.946 us; speedup 1.0000x reference)
//
#include <hip/hip_runtime.h>

// Chamfer loss, B=8, N=M=8192, D=3, fp32.
// d = ||g||^2 + ||p||^2 - 2 g.p. Scanned points precomputed as
// (-2x,-2y,-2z,||x||^2) so inner pair = 3 FMA + 1 min; owner norm added after.

#define TILE 256
#define U 4
#define SPLIT 8

__device__ __forceinline__ unsigned enc_f32(float f) {
  unsigned b = __float_as_uint(f);
  return (b & 0x80000000u) ? ~b : (b | 0x80000000u);
}
__device__ __forceinline__ float dec_f32(unsigned u) {
  unsigned b = (u & 0x80000000u) ? (u ^ 0x80000000u) : ~u;
  return __uint_as_float(b);
}

__global__ void transform_kernel(const float* __restrict__ pts,
                                 float4* __restrict__ out, int n) {
  int i = blockIdx.x * blockDim.x + threadIdx.x;
  if (i >= n) return;
  float x = pts[3 * i + 0], y = pts[3 * i + 1], z = pts[3 * i + 2];
  out[i] = make_float4(-2.0f * x, -2.0f * y, -2.0f * z,
                       fmaf(x, x, fmaf(y, y, z * z)));
}

// Each block: 256 threads x U owned points, scans a 1/SPLIT slice of the
// scanned set for one batch. Partial mins merged via encoded atomicMin.
__global__ __launch_bounds__(256) void chamfer_min_kernel(
    const float4* __restrict__ scan, const float4* __restrict__ own,
    unsigned* __restrict__ mins, int nScan, int nOwn) {
  __shared__ float4 tile[TILE];
  const int tid = threadIdx.x;
  const int ownPerBlock = 256 * U;
  const int ownChunks = nOwn / ownPerBlock;
  const int blocksPerB = ownChunks * SPLIT;
  const int b = blockIdx.x / blocksPerB;
  const int r = blockIdx.x % blocksPerB;
  const int oc = r / SPLIT;
  const int sp = r % SPLIT;
  const int scanLen = nScan / SPLIT;

  const float4* ownBase = own + (size_t)b * nOwn + oc * ownPerBlock;
  const float4* scanBase = scan + (size_t)b * nScan + sp * scanLen;

  float px[U], py[U], pz[U], pw[U], m[U];
#pragma unroll
  for (int k = 0; k < U; ++k) {
    float4 t = ownBase[k * 256 + tid];
    // recover raw coords from the (-2x,...) transform
    px[k] = -0.5f * t.x;
    py[k] = -0.5f * t.y;
    pz[k] = -0.5f * t.z;
    pw[k] = t.w;  // ||p||^2, added after the min
    m[k] = 3.0e38f;
  }

  for (int t0 = 0; t0 < scanLen; t0 += TILE) {
    __syncthreads();
    tile[tid] = scanBase[t0 + tid];
    __syncthreads();
#pragma unroll 8
    for (int t = 0; t < TILE; ++t) {
      float4 s = tile[t];
#pragma unroll
      for (int k = 0; k < U; ++k) {
        float v = fmaf(px[k], s.x, fmaf(py[k], s.y, fmaf(pz[k], s.z, s.w)));
        m[k] = fminf(m[k], v);
      }
    }
  }

  unsigned* minBase = mins + (size_t)b * nOwn + oc * ownPerBlock;
#pragma unroll
  for (int k = 0; k < U; ++k) {
    atomicMin(&minBase[k * 256 + tid], enc_f32(m[k] + pw[k]));
  }
}

__global__ __launch_bounds__(1024) void reduce_kernel(
    const unsigned* __restrict__ mins, int n, float* __restrict__ out) {
  __shared__ float partial[16];
  float s = 0.0f;
  for (int i = threadIdx.x; i < n; i += 1024) s += dec_f32(mins[i]);
#pragma unroll
  for (int off = 32; off > 0; off >>= 1) s += __shfl_down(s, off, 64);
  int wid = threadIdx.x >> 6, lane = threadIdx.x & 63;
  if (lane == 0) partial[wid] = s;
  __syncthreads();
  if (threadIdx.x == 0) {
    float tot = 0.0f;
#pragma unroll
    for (int w = 0; w < 16; ++w) tot += partial[w];
    out[0] = tot;
  }
}

extern "C" void kernel_launch(void* const* d_in, const int* in_sizes, int n_in,
                              void* d_out, int out_size, void* d_ws,
                              size_t ws_size, hipStream_t stream) {
  const float* preds = (const float*)d_in[0];  // [B, M, 3]
  const float* gts = (const float*)d_in[1];    // [B, N, 3]
  const int B = 8;
  const int M = in_sizes[0] / (3 * B);
  const int N = in_sizes[1] / (3 * B);

  // ws layout: minsP [B*M] u32 | minsG [B*N] u32 | Tg [B*N] f4 | Tp [B*M] f4
  unsigned* minsP = (unsigned*)d_ws;
  unsigned* minsG = minsP + (size_t)B * M;
  float4* Tg = (float4*)(minsG + (size_t)B * N);
  float4* Tp = Tg + (size_t)B * N;

  // init mins to "encoded +inf" (0xFFFFFFFF)
  hipMemsetAsync(d_ws, 0xFF, (size_t)(B * M + B * N) * sizeof(unsigned), stream);

  transform_kernel<<<(B * M + 255) / 256, 256, 0, stream>>>(preds, Tp, B * M);
  transform_kernel<<<(B * N + 255) / 256, 256, 0, stream>>>(gts, Tg, B * N);

  // loss_1: for each pred, nearest gt (own = preds, scan = gts)
  chamfer_min_kernel<<<B * (M / (256 * U)) * SPLIT, 256, 0, stream>>>(
      Tg, Tp, minsP, N, M);
  // loss_2: for each gt, nearest pred
  chamfer_min_kernel<<<B * (N / (256 * U)) * SPLIT, 256, 0, stream>>>(
      Tp, Tg, minsG, M, N);

  reduce_kernel<<<1, 1024, 0, stream>>>((unsigned*)d_ws, B * (M + N),
                                        (float*)d_out);
}

// Round 3
// 101.908 us; speedup vs baseline: 1.3438x; 1.3438x over previous
//
#include <hip/hip_runtime.h>

// Chamfer loss, B=8, N=M=8192, D=3, fp32.
// d(p,g) = ||g||^2 - 2 p.g + ||p||^2. Points precomputed as
// (-2x,-2y,-2z,||x||^2); inner pair = 3 FMA + 1 min; own norm added after min.
// One merged kernel does both directions; partial mins written non-atomically
// to ws [dir][SPLIT][B*8192]; reduce = min over SPLIT + sum.

#define TILE 256
#define U 8
#define SPLIT 8
#define NPTS 8192      // N == M
#define BATCH 8
#define PER_DIR (BATCH * NPTS)  // 65536 owned slots per direction

__global__ __launch_bounds__(256) void transform_kernel(
    const float* __restrict__ preds, const float* __restrict__ gts,
    float4* __restrict__ Tp, float4* __restrict__ Tg) {
  int i = blockIdx.x * blockDim.x + threadIdx.x;  // 0 .. 2*PER_DIR-1
  const float* src;
  float4* dst;
  int j;
  if (i < PER_DIR) {
    src = preds; dst = Tp; j = i;
  } else {
    src = gts; dst = Tg; j = i - PER_DIR;
  }
  float x = src[3 * j + 0], y = src[3 * j + 1], z = src[3 * j + 2];
  dst[j] = make_float4(-2.0f * x, -2.0f * y, -2.0f * z,
                       fmaf(x, x, fmaf(y, y, z * z)));
}

// grid = 2 * BATCH * (NPTS/(256*U)) * SPLIT = 512 blocks (2 per CU, all resident)
__global__ __launch_bounds__(256) void chamfer_min_kernel(
    const float4* __restrict__ Tg, const float4* __restrict__ Tp,
    float* __restrict__ partP, float* __restrict__ partG) {
  __shared__ float4 tile[TILE];
  const int tid = threadIdx.x;
  const int ownPerBlock = 256 * U;              // 2048
  const int ownChunks = NPTS / ownPerBlock;     // 4
  const int blocksPerDir = BATCH * ownChunks * SPLIT;  // 256

  int id = blockIdx.x;
  const int dir = id / blocksPerDir;
  id %= blocksPerDir;
  const int b = id / (ownChunks * SPLIT);
  const int r = id % (ownChunks * SPLIT);
  const int oc = r / SPLIT;
  const int sp = r % SPLIT;
  const int scanLen = NPTS / SPLIT;             // 1024

  const float4* own = (dir == 0 ? Tp : Tg) + (size_t)b * NPTS + oc * ownPerBlock;
  const float4* scan = (dir == 0 ? Tg : Tp) + (size_t)b * NPTS + sp * scanLen;
  float* outp = (dir == 0 ? partP : partG) + (size_t)sp * PER_DIR +
                (size_t)b * NPTS + oc * ownPerBlock;

  float px[U], py[U], pz[U], pw[U], m[U];
#pragma unroll
  for (int k = 0; k < U; ++k) {
    float4 t = own[k * 256 + tid];
    px[k] = -0.5f * t.x;   // recover raw coords from (-2x,...) form
    py[k] = -0.5f * t.y;
    pz[k] = -0.5f * t.z;
    pw[k] = t.w;           // ||p||^2, added after the min
    m[k] = 3.0e38f;
  }

  for (int t0 = 0; t0 < scanLen; t0 += TILE) {
    __syncthreads();
    tile[tid] = scan[t0 + tid];
    __syncthreads();
#pragma unroll 8
    for (int t = 0; t < TILE; ++t) {
      float4 s = tile[t];
#pragma unroll
      for (int k = 0; k < U; ++k) {
        float v = fmaf(px[k], s.x, fmaf(py[k], s.y, fmaf(pz[k], s.z, s.w)));
        m[k] = fminf(m[k], v);
      }
    }
  }

#pragma unroll
  for (int k = 0; k < U; ++k) {
    outp[k * 256 + tid] = m[k] + pw[k];
  }
}

// Stage A: min over SPLIT partials per owned slot, sum per block.
// partial layout: [2][SPLIT][PER_DIR]. 128 blocks x 256 threads.
__global__ __launch_bounds__(256) void reduce_a_kernel(
    const float* __restrict__ partial, float* __restrict__ blockSums) {
  const int nSlots = 2 * PER_DIR;  // 131072
  const int gid = blockIdx.x * 256 + threadIdx.x;
  const int stride = 128 * 256;
  float s = 0.0f;
  for (int sl = gid; sl < nSlots; sl += stride) {
    const int dir = sl >> 16;          // PER_DIR == 65536
    const int idx = sl & (PER_DIR - 1);
    const float* base = partial + (size_t)dir * SPLIT * PER_DIR + idx;
    float mn = base[0];
#pragma unroll
    for (int sp = 1; sp < SPLIT; ++sp) mn = fminf(mn, base[(size_t)sp * PER_DIR]);
    s += mn;
  }
#pragma unroll
  for (int off = 32; off > 0; off >>= 1) s += __shfl_down(s, off, 64);
  __shared__ float part[4];
  int wid = threadIdx.x >> 6, lane = threadIdx.x & 63;
  if (lane == 0) part[wid] = s;
  __syncthreads();
  if (threadIdx.x == 0) {
    blockSums[blockIdx.x] = part[0] + part[1] + part[2] + part[3];
  }
}

__global__ __launch_bounds__(128) void reduce_b_kernel(
    const float* __restrict__ blockSums, float* __restrict__ out) {
  float s = blockSums[threadIdx.x];
#pragma unroll
  for (int off = 32; off > 0; off >>= 1) s += __shfl_down(s, off, 64);
  __shared__ float part[2];
  int wid = threadIdx.x >> 6, lane = threadIdx.x & 63;
  if (lane == 0) part[wid] = s;
  __syncthreads();
  if (threadIdx.x == 0) out[0] = part[0] + part[1];
}

extern "C" void kernel_launch(void* const* d_in, const int* in_sizes, int n_in,
                              void* d_out, int out_size, void* d_ws,
                              size_t ws_size, hipStream_t stream) {
  const float* preds = (const float*)d_in[0];  // [B, M, 3]
  const float* gts = (const float*)d_in[1];    // [B, N, 3]

  // ws layout: partial [2][SPLIT][PER_DIR] f32 (4 MB) | blockSums[128] f32 |
  //            Tp [PER_DIR] f4 (1 MB) | Tg [PER_DIR] f4 (1 MB)
  float* partial = (float*)d_ws;
  float* blockSums = partial + (size_t)2 * SPLIT * PER_DIR;
  float4* Tp = (float4*)(blockSums + 128);
  float4* Tg = Tp + PER_DIR;

  transform_kernel<<<2 * PER_DIR / 256, 256, 0, stream>>>(preds, gts, Tp, Tg);

  const int ownChunks = NPTS / (256 * U);  // 4
  chamfer_min_kernel<<<2 * BATCH * ownChunks * SPLIT, 256, 0, stream>>>(
      Tg, Tp, partial, partial + (size_t)SPLIT * PER_DIR);

  reduce_a_kernel<<<128, 256, 0, stream>>>(partial, blockSums);
  reduce_b_kernel<<<1, 128, 0, stream>>>(blockSums, (float*)d_out);
}